// Round 10
// baseline (153.707 us; speedup 1.0000x reference)
//
#include <hip/hip_runtime.h>
#include <hip/hip_fp16.h>

typedef __attribute__((ext_vector_type(8))) _Float16 f16x8;
typedef __attribute__((ext_vector_type(4))) float f32x4;

#define MFMA16(a, b, c) __builtin_amdgcn_mfma_f32_16x16x32_f16((a), (b), (c), 0, 0, 0)

__device__ __forceinline__ unsigned short f2h(float f) {
  __half h = __float2half(f);
  return __half_as_ushort(h);
}

__device__ __forceinline__ void gll16(const void* g, void* l) {
  __builtin_amdgcn_global_load_lds(
      (const __attribute__((address_space(1))) unsigned int*)g,
      (__attribute__((address_space(3))) unsigned int*)l, 16, 0, 0);
}

// ---------------- f32 -> fp16 convert (vectorized) ----------------
__global__ void cvt_f16_kernel(const float* __restrict__ X, unsigned short* __restrict__ Y) {
  size_t i = ((size_t)blockIdx.x * blockDim.x + threadIdx.x) * 4;
  float4 v = *reinterpret_cast<const float4*>(X + i);
  ushort4 o;
  o.x = f2h(v.x); o.y = f2h(v.y); o.z = f2h(v.z); o.w = f2h(v.w);
  *reinterpret_cast<ushort4*>(Y + i) = o;
}

// ---------------- batched weight transpose f32(1024x1024) -> fp16(1024x1024)^T ----------------
__global__ void transpose_w4_kernel(const float* __restrict__ W0, const float* __restrict__ W1,
                                    const float* __restrict__ W2, const float* __restrict__ W3,
                                    unsigned short* __restrict__ T0, unsigned short* __restrict__ T1,
                                    unsigned short* __restrict__ T2, unsigned short* __restrict__ T3) {
  __shared__ float tile[32][33];
  int z = blockIdx.z;
  const float* W = (z == 0) ? W0 : ((z == 1) ? W1 : ((z == 2) ? W2 : W3));
  unsigned short* WT = (z == 0) ? T0 : ((z == 1) ? T1 : ((z == 2) ? T2 : T3));
  int c0 = blockIdx.x * 32, r0 = blockIdx.y * 32;
  int tx = threadIdx.x, ty = threadIdx.y;  // 32 x 8
#pragma unroll
  for (int i = 0; i < 32; i += 8)
    tile[ty + i][tx] = W[(size_t)(r0 + ty + i) * 1024 + c0 + tx];
  __syncthreads();
#pragma unroll
  for (int i = 0; i < 32; i += 8)
    WT[(size_t)(c0 + ty + i) * 1024 + r0 + tx] = f2h(tile[tx][ty + i]);
}

// ---------------- rel weight transpose f32(192x1024) -> fp16(1024x192) ----------------
__global__ void transpose_wr_kernel(const float* __restrict__ W, unsigned short* __restrict__ WT) {
  __shared__ float tile[32][33];
  int c0 = blockIdx.x * 32, r0 = blockIdx.y * 32;
  int tx = threadIdx.x, ty = threadIdx.y;
#pragma unroll
  for (int i = 0; i < 32; i += 8)
    tile[ty + i][tx] = W[(size_t)(r0 + ty + i) * 1024 + c0 + tx];
  __syncthreads();
#pragma unroll
  for (int i = 0; i < 32; i += 8)
    WT[(size_t)(c0 + ty + i) * 192 + r0 + tx] = f2h(tile[tx][ty + i]);
}

// ---------------- positional embedding: pos[2048][192] fp16 (row 2047 = 0) ----------------
__global__ void posembed_kernel(unsigned short* __restrict__ pos) {
  int d = blockIdx.x * blockDim.x + threadIdx.x;
  if (d >= 2048) return;
  unsigned short* row = pos + (size_t)d * 192;
  if (d == 2047) {
    for (int j = 0; j < 192; ++j) row[j] = 0;
    return;
  }
  float dist = (float)d - 1023.0f;
  float absd = fabsf(dist);
  float sgnp = (dist > 0.0f) ? 1.0f : ((dist < 0.0f) ? -1.0f : 0.0f);
  float gam[32];
  float maxp = 0.0f;
#pragma unroll
  for (int j = 0; j < 32; ++j) {
    float hl = exp2f(3.0f + (float)j * (7.0f / 31.0f));
    float fe = exp2f(-absd / hl);
    float cw = exp2f((float)(j + 1)) - 1.0f;
    float fc = (cw > absd) ? 1.0f : 0.0f;
    float jp = (float)(j + 1);
    float conc = 4.0f * jp * jp;
    float rate = 0.125f * jp;
    float lu = (conc - 1.0f) * logf(absd) - rate * absd;
    float ln_ = lgammaf(conc) - conc * logf(rate);
    float p = expf(lu - ln_) + 1e-8f;
    gam[j] = p;
    maxp = fmaxf(maxp, p);
    row[j] = f2h(fe);
    row[32 + j] = f2h(fc);
  }
  float inv = 1.0f / maxp;
#pragma unroll
  for (int j = 0; j < 32; ++j) row[64 + j] = f2h(gam[j] * inv);
  for (int j = 0; j < 96; ++j) {
    unsigned short v = row[j];
    unsigned short o;
    if (sgnp == 0.0f) o = 0;
    else if (sgnp > 0.0f) o = v;
    else o = (unsigned short)(v ^ 0x8000u);
    row[96 + j] = o;
  }
}

// ---------------- fp16 GEMM (m97 structure): C = A[M,K] @ BT[N,K]^T ----------------
__global__ __launch_bounds__(256) void gemm16_kernel(
    const unsigned short* __restrict__ A,
    const unsigned short* __restrict__ BT0, const unsigned short* __restrict__ BT1,
    const unsigned short* __restrict__ BT2,
    unsigned short* __restrict__ D0, unsigned short* __restrict__ D1,
    unsigned short* __restrict__ D2,
    float* __restrict__ C32, const float* __restrict__ bias,
    int M, int N, int K) {
  __shared__ unsigned short As[128][64];  // linear (gll dest), logically XOR-swizzled
  __shared__ unsigned short Bs[128][64];
  const unsigned short* BT = (blockIdx.z == 0) ? BT0 : ((blockIdx.z == 1) ? BT1 : BT2);
  unsigned short* D = (blockIdx.z == 0) ? D0 : ((blockIdx.z == 1) ? D1 : D2);

  int tid = threadIdx.x, wave = tid >> 6, lane = tid & 63;
  int g = lane >> 4, r16 = lane & 15;
  int wr = wave >> 1, wc = wave & 1;
  int m0 = blockIdx.x * 128, n0 = blockIdx.y * 128;
  int srow = wave * 32 + (lane >> 3);  // + 8*i
  int scb = lane & 7;                  // physical 16B slot within row

  f32x4 acc[4][4] = {};

  for (int k0 = 0; k0 < K; k0 += 64) {
    __syncthreads();
#pragma unroll
    for (int i = 0; i < 4; ++i) {
      int row = srow + i * 8;
      int cb = scb ^ (row & 7);  // pre-swizzled global source, linear LDS dest
      gll16(A + (size_t)(m0 + row) * K + k0 + cb * 8, &As[row][scb * 8]);
      gll16(BT + (size_t)(n0 + row) * K + k0 + cb * 8, &Bs[row][scb * 8]);
    }
    asm volatile("s_waitcnt vmcnt(0)" ::: "memory");
    __syncthreads();

    f16x8 af[2][4], bfr[2][4];
#pragma unroll
    for (int kf = 0; kf < 2; ++kf) {
#pragma unroll
      for (int mt = 0; mt < 4; ++mt) {
        int R = wr * 64 + mt * 16 + r16;
        af[kf][mt] = *reinterpret_cast<const f16x8*>(&As[R][(((kf * 4 + g)) ^ (R & 7)) * 8]);
      }
#pragma unroll
      for (int nt = 0; nt < 4; ++nt) {
        int R = wc * 64 + nt * 16 + r16;
        bfr[kf][nt] = *reinterpret_cast<const f16x8*>(&Bs[R][(((kf * 4 + g)) ^ (R & 7)) * 8]);
      }
    }
#pragma unroll
    for (int kf = 0; kf < 2; ++kf)
#pragma unroll
      for (int mt = 0; mt < 4; ++mt)
#pragma unroll
        for (int nt = 0; nt < 4; ++nt)
          acc[mt][nt] = MFMA16(af[kf][mt], bfr[kf][nt], acc[mt][nt]);
  }

#pragma unroll
  for (int nt = 0; nt < 4; ++nt) {
    int col = n0 + wc * 64 + nt * 16 + r16;
    float bv = (C32 && bias) ? bias[col] : 0.0f;
#pragma unroll
    for (int mt = 0; mt < 4; ++mt) {
      int rowb = m0 + wr * 64 + mt * 16 + g * 4;
      if (C32) {
#pragma unroll
        for (int rg = 0; rg < 4; ++rg)
          C32[(size_t)(rowb + rg) * N + col] = acc[mt][nt][rg] + bv;
      } else {
#pragma unroll
        for (int rg = 0; rg < 4; ++rg)
          D[(size_t)(rowb + rg) * N + col] = f2h(acc[mt][nt][rg]);
      }
    }
  }
}

// ---------------- V transpose prep: Vh fp16 (2048x1024) -> Vt fp16 [bh][128][1024] ----------------
__global__ void vt_prep_kernel(const unsigned short* __restrict__ Vh, unsigned short* __restrict__ Vt) {
  __shared__ unsigned short tile[32][34];
  int bh = blockIdx.z;
  int b = bh >> 3, h = bh & 7;
  int l0 = blockIdx.x * 32, n0 = blockIdx.y * 32;
  int tx = threadIdx.x, ty = threadIdx.y;
#pragma unroll
  for (int i = 0; i < 32; i += 8)
    tile[ty + i][tx] = Vh[(size_t)(b * 1024 + l0 + ty + i) * 1024 + h * 128 + n0 + tx];
  __syncthreads();
#pragma unroll
  for (int i = 0; i < 32; i += 8)
    Vt[(size_t)bh * 131072 + (size_t)(n0 + ty + i) * 1024 + l0 + tx] = tile[tx][ty + i];
}

// ---------------- fused attention v6: 2-phase pipeline, R ring, deferred softmax ----------------
// grid (L/64, 2, B*H); 4 waves; wave owns 16 q rows; BK=32; online softmax.
// Per iter: vmcnt(0) -> ds_write V[t] -> barrier -> issue K/R/V[t+1] -> compute t.
__global__ __launch_bounds__(256) void attn_kernel(
    const unsigned short* __restrict__ Qh, const unsigned short* __restrict__ Kh,
    const unsigned short* __restrict__ Vt, const unsigned short* __restrict__ relkh,
    const float* __restrict__ eb, const float* __restrict__ pb,
    unsigned short* __restrict__ Opart, float* __restrict__ mlpart) {
  __shared__ unsigned short Ks[2][32 * 128];   // 16KB dbuf, swizzled slots
  __shared__ unsigned short Rs[128 * 128];     // 32KB ring (slot = row & 127), swizzled slots
  __shared__ unsigned short Vs[2][128][40];    // 20KB dbuf, padded
  __shared__ unsigned short Ps[4][16][42];     // 5.25KB

  int tid = threadIdx.x;
  int wave = tid >> 6, lane = tid & 63;
  int g = lane >> 4, r16 = lane & 15;
  int ks = blockIdx.y;
  int bh = blockIdx.z;
  int b = bh >> 3, h = bh & 7;
  int q0 = blockIdx.x * 64;
  int q0w = q0 + wave * 16;
  const float scale = 0.0883883476483184f;  // 128^-0.5

  // ---- Q fragments (A-layout: row = lane&15, k = (lane>>4)*8+i), two bias variants
  f16x8 qa[4], qbv[4];
  {
    int qrow = b * 1024 + q0w + r16;
    const unsigned short* qp = Qh + (size_t)qrow * 1024 + h * 128;
    const float* ebp = eb + h * 128;
    const float* pbp = pb + h * 128;
#pragma unroll
    for (int kf = 0; kf < 4; ++kf) {
      int dbase = kf * 32 + g * 8;
      uint4 qv = *reinterpret_cast<const uint4*>(qp + dbase);
      const __half* hv = reinterpret_cast<const __half*>(&qv);
      float4 e0 = *reinterpret_cast<const float4*>(ebp + dbase);
      float4 e1 = *reinterpret_cast<const float4*>(ebp + dbase + 4);
      float4 c0 = *reinterpret_cast<const float4*>(pbp + dbase);
      float4 c1 = *reinterpret_cast<const float4*>(pbp + dbase + 4);
      float ev[8] = {e0.x, e0.y, e0.z, e0.w, e1.x, e1.y, e1.z, e1.w};
      float bv[8] = {c0.x, c0.y, c0.z, c0.w, c1.x, c1.y, c1.z, c1.w};
      unsigned short ta[8], tb[8];
#pragma unroll
      for (int i = 0; i < 8; ++i) {
        float s = __half2float(hv[i]) * scale;
        ta[i] = f2h(s + ev[i]);
        tb[i] = f2h(s + bv[i]);
      }
      qa[kf] = *reinterpret_cast<f16x8*>(ta);
      qbv[kf] = *reinterpret_cast<f16x8*>(tb);
    }
  }

  float m_run[4], l_part[4];
#pragma unroll
  for (int rg = 0; rg < 4; ++rg) { m_run[rg] = -1e30f; l_part[rg] = 0.0f; }
  f32x4 o_acc[8] = {};

  const unsigned short* KB = Kh + ((size_t)b * 1024) * 1024 + h * 128;
  const unsigned short* VB = Vt + (size_t)bh * 131072;
  const unsigned short* RB = relkh + h * 128;
  int wb = 48 - wave * 16;

  const int t0 = ks * 16, t1 = t0 + 16;
  const int rb0 = 960 + t0 * 32 - q0;

  // ---- prologue: issue K[t0] (2 gll), R window [rb0, rb0+96) (6 gll), V[t0] (2 reg loads)
  uint4 va, vb2;
#pragma unroll
  for (int i = 0; i < 2; ++i) {
    int j = i * 256 + tid;
    int row = j >> 4, s = j & 15, c = s ^ (row & 7);
    gll16(KB + (size_t)(t0 * 32 + row) * 1024 + c * 8, &Ks[t0 & 1][(row * 16 + s) * 8]);
  }
#pragma unroll
  for (int i = 0; i < 6; ++i) {
    int j = i * 256 + tid;
    int row = rb0 + (j >> 4);
    int s = j & 15, c = s ^ (row & 7);
    gll16(RB + (size_t)row * 1024 + c * 8, &Rs[(((row & 127) * 16) + s) * 8]);
  }
  {
    const unsigned short* src = VB + (size_t)(tid >> 1) * 1024 + t0 * 32 + (tid & 1) * 16;
    va = *reinterpret_cast<const uint4*>(src);
    vb2 = *reinterpret_cast<const uint4*>(src + 8);
  }

  for (int t = t0; t < t1; ++t) {
    int cur = t & 1;
    asm volatile("s_waitcnt vmcnt(0)" ::: "memory");
    // write V[t] into dbuf
    {
      int rr = tid >> 1, cc = (tid & 1) * 16;
      *reinterpret_cast<uint4*>(&Vs[cur][rr][cc]) = va;
      *reinterpret_cast<uint4*>(&Vs[cur][rr][cc + 8]) = vb2;
    }
    __syncthreads();

    // ---- issue next tile's loads (stay in flight across compute)
    if (t + 1 < t1) {
      int nk0 = (t + 1) * 32;
#pragma unroll
      for (int i = 0; i < 2; ++i) {
        int j = i * 256 + tid;
        int row = j >> 4, s = j & 15, c = s ^ (row & 7);
        gll16(KB + (size_t)(nk0 + row) * 1024 + c * 8, &Ks[(t + 1) & 1][(row * 16 + s) * 8]);
      }
      int rnew = rb0 + 96 + (t - t0) * 32;
#pragma unroll
      for (int i = 0; i < 2; ++i) {
        int j = i * 256 + tid;
        int row = rnew + (j >> 4);
        int s = j & 15, c = s ^ (row & 7);
        gll16(RB + (size_t)row * 1024 + c * 8, &Rs[(((row & 127) * 16) + s) * 8]);
      }
      const unsigned short* src = VB + (size_t)(tid >> 1) * 1024 + nk0 + (tid & 1) * 16;
      va = *reinterpret_cast<const uint4*>(src);
      vb2 = *reinterpret_cast<const uint4*>(src + 8);
    }

    // ---- compute tile t
    int k0 = t * 32;
    int rbt = rb0 + (t - t0) * 32;
    f32x4 s0 = {0.f, 0.f, 0.f, 0.f}, s1 = {0.f, 0.f, 0.f, 0.f};
    f32x4 w0 = {0.f, 0.f, 0.f, 0.f}, w1 = {0.f, 0.f, 0.f, 0.f}, w2 = {0.f, 0.f, 0.f, 0.f};
#pragma unroll
    for (int kf = 0; kf < 4; ++kf) {
      int sl = kf * 4 + g;
      int x = sl ^ (r16 & 7);
      f16x8 kb0 = *reinterpret_cast<const f16x8*>(&Ks[cur][(r16 * 16 + x) * 8]);
      f16x8 kb1 = *reinterpret_cast<const f16x8*>(&Ks[cur][((16 + r16) * 16 + x) * 8]);
      s0 = MFMA16(qa[kf], kb0, s0);
      s1 = MFMA16(qa[kf], kb1, s1);
      int R0 = rbt + wb + r16, R1 = R0 + 16, R2 = R0 + 32;
      f16x8 rb_0 = *reinterpret_cast<const f16x8*>(&Rs[((R0 & 127) * 16 + (sl ^ (R0 & 7))) * 8]);
      f16x8 rb_1 = *reinterpret_cast<const f16x8*>(&Rs[((R1 & 127) * 16 + (sl ^ (R1 & 7))) * 8]);
      f16x8 rb_2 = *reinterpret_cast<const f16x8*>(&Rs[((R2 & 127) * 16 + (sl ^ (R2 & 7))) * 8]);
      w0 = MFMA16(qbv[kf], rb_0, w0);
      w1 = MFMA16(qbv[kf], rb_1, w1);
      w2 = MFMA16(qbv[kf], rb_2, w2);
    }

    // ---- diagonal gather via funnel shuffle: S2[q'][k'] = W[q'][k'-q'+15]
    float sv[2][4];
#pragma unroll
    for (int rg = 0; rg < 4; ++rg) {
      int qp = g * 4 + rg;
      int idx = r16 + 15 - qp;                  // 0..30
      int srcl = (lane & 48) | (idx & 15);
      float a0 = __shfl(w0[rg], srcl);
      float a1 = __shfl(w1[rg], srcl);
      float a2 = __shfl(w2[rg], srcl);
      bool lo = idx < 16;
      sv[0][rg] = s0[rg] + (lo ? a0 : a1);
      sv[1][rg] = s1[rg] + (lo ? a1 : a2);
    }

    // ---- deferred softmax: conditional rescale (T13), per-lane partial l
    float d = -1e30f;
#pragma unroll
    for (int rg = 0; rg < 4; ++rg)
      d = fmaxf(d, fmaxf(sv[0][rg], sv[1][rg]) - m_run[rg]);
    if (!__all(d <= 8.0f)) {
#pragma unroll
      for (int rg = 0; rg < 4; ++rg) {
        float mx = fmaxf(sv[0][rg], sv[1][rg]);
#pragma unroll
        for (int off = 8; off >= 1; off >>= 1) mx = fmaxf(mx, __shfl_xor(mx, off));
        float mnew = fmaxf(m_run[rg], mx);
        float scl = __expf(m_run[rg] - mnew);
        l_part[rg] *= scl;
#pragma unroll
        for (int nf = 0; nf < 8; ++nf) o_acc[nf][rg] *= scl;
        m_run[rg] = mnew;
      }
    }
#pragma unroll
    for (int rg = 0; rg < 4; ++rg) {
      float e0 = __expf(sv[0][rg] - m_run[rg]);
      float e1 = __expf(sv[1][rg] - m_run[rg]);
      l_part[rg] += e0 + e1;
      Ps[wave][g * 4 + rg][r16] = f2h(e0);
      Ps[wave][g * 4 + rg][16 + r16] = f2h(e1);
    }
    // ---- PV: O += P (16x32) . V (32x128)
    f16x8 pf = *reinterpret_cast<const f16x8*>(&Ps[wave][r16][g * 8]);
#pragma unroll
    for (int nf = 0; nf < 8; ++nf) {
      f16x8 vb = *reinterpret_cast<const f16x8*>(&Vs[cur][nf * 16 + r16][g * 8]);
      o_acc[nf] = MFMA16(pf, vb, o_acc[nf]);
    }
  }

  // ---- final l reduction across the 16-lane row group
  float l_run[4];
#pragma unroll
  for (int rg = 0; rg < 4; ++rg) {
    float rs = l_part[rg];
#pragma unroll
    for (int off = 8; off >= 1; off >>= 1) rs += __shfl_xor(rs, off);
    l_run[rg] = rs;
  }

  // epilogue: write unnormalized O (fp16) + (m,l) partials
  size_t slice = (size_t)(ks * 16 + bh);
#pragma unroll
  for (int rg = 0; rg < 4; ++rg) {
    unsigned short* op = Opart + (slice * 1024 + q0w + g * 4 + rg) * 128;
#pragma unroll
    for (int nf = 0; nf < 8; ++nf) op[nf * 16 + r16] = f2h(o_acc[nf][rg]);
  }
  if (r16 == 0) {
#pragma unroll
    for (int rg = 0; rg < 4; ++rg) {
      float2 ml = {m_run[rg], l_run[rg]};
      *reinterpret_cast<float2*>(mlpart + (slice * 1024 + q0w + g * 4 + rg) * 2) = ml;
    }
  }
}

// ---------------- combine two k-slices -> attnO fp16 ----------------
__global__ void combine_kernel(const unsigned short* __restrict__ Opart,
                               const float* __restrict__ mlpart,
                               unsigned short* __restrict__ attnO) {
  int idx = blockIdx.x * 256 + threadIdx.x;  // 16*1024*32 threads
  int d4 = (idx & 31) * 4;
  int qq = (idx >> 5) & 1023;
  int bh = idx >> 15;
  float2 ml[2];
  float m = -1e30f;
#pragma unroll
  for (int s = 0; s < 2; ++s) {
    ml[s] = *reinterpret_cast<const float2*>(mlpart + (((size_t)(s * 16 + bh)) * 1024 + qq) * 2);
    m = fmaxf(m, ml[s].x);
  }
  float num0 = 0.f, num1 = 0.f, num2 = 0.f, num3 = 0.f, den = 0.f;
#pragma unroll
  for (int s = 0; s < 2; ++s) {
    float w = __expf(ml[s].x - m);
    den += w * ml[s].y;
    ushort4 ov = *reinterpret_cast<const ushort4*>(
        Opart + (((size_t)(s * 16 + bh)) * 1024 + qq) * 128 + d4);
    num0 += w * __half2float(__ushort_as_half(ov.x));
    num1 += w * __half2float(__ushort_as_half(ov.y));
    num2 += w * __half2float(__ushort_as_half(ov.z));
    num3 += w * __half2float(__ushort_as_half(ov.w));
  }
  float inv = 1.0f / den;
  ushort4 o;
  o.x = f2h(num0 * inv); o.y = f2h(num1 * inv);
  o.z = f2h(num2 * inv); o.w = f2h(num3 * inv);
  int b = bh >> 3, h = bh & 7;
  *reinterpret_cast<ushort4*>(attnO + ((size_t)(b * 1024 + qq)) * 1024 + h * 128 + d4) = o;
}

// ---------------- launch ----------------
extern "C" void kernel_launch(void* const* d_in, const int* in_sizes, int n_in,
                              void* d_out, int out_size, void* d_ws, size_t ws_size,
                              hipStream_t stream) {
  const float* q      = (const float*)d_in[0];
  const float* w_qs   = (const float*)d_in[1];
  const float* w_ks   = (const float*)d_in[2];
  const float* w_vs   = (const float*)d_in[3];
  const float* w_rel  = (const float*)d_in[4];
  const float* ebias  = (const float*)d_in[5];
  const float* pbias  = (const float*)d_in[6];
  const float* w_out  = (const float*)d_in[7];
  const float* b_out  = (const float*)d_in[8];
  float* out = (float*)d_out;

  char* ws = (char*)d_ws;
  const size_t MB = 1u << 20;
  unsigned short* Xh    = (unsigned short*)(ws + 0 * MB);   // 2048x1024 fp16
  unsigned short* WqsT  = (unsigned short*)(ws + 4 * MB);
  unsigned short* WksT  = (unsigned short*)(ws + 6 * MB);
  unsigned short* WvsT  = (unsigned short*)(ws + 8 * MB);
  unsigned short* WoutT = (unsigned short*)(ws + 10 * MB);
  unsigned short* WrelT = (unsigned short*)(ws + 12 * MB);  // 1024x192
  unsigned short* pos   = (unsigned short*)(ws + 13 * MB);  // 2048x192
  unsigned short* Qh    = (unsigned short*)(ws + 14 * MB);  // 2048x1024 fp16
  unsigned short* Kh    = (unsigned short*)(ws + 18 * MB);
  unsigned short* Vh    = (unsigned short*)(ws + 22 * MB);
  unsigned short* relkh = (unsigned short*)(ws + 26 * MB);  // 2048x1024 fp16
  unsigned short* Vt    = (unsigned short*)(ws + 30 * MB);  // 16x128x1024 fp16
  unsigned short* attnO = (unsigned short*)(ws + 34 * MB);  // 2048x1024 fp16
  unsigned short* Opart = (unsigned short*)(ws + 38 * MB);  // 2x16x1024x128 fp16 (8MB)
  float* mlpart         = (float*)(ws + 50 * MB);           // 2x16x1024x2 f32

  // 1. converts / transposes / positional embed
  cvt_f16_kernel<<<2048, 256, 0, stream>>>(q, Xh);
  transpose_w4_kernel<<<dim3(32, 32, 4), dim3(32, 8), 0, stream>>>(
      w_qs, w_ks, w_vs, w_out, WqsT, WksT, WvsT, WoutT);
  transpose_wr_kernel<<<dim3(32, 6), dim3(32, 8), 0, stream>>>(w_rel, WrelT);
  posembed_kernel<<<8, 256, 0, stream>>>(pos);

  // 2. projections (QKV batched via grid.z) + rel_k, fp16 outputs
  gemm16_kernel<<<dim3(16, 8, 3), 256, 0, stream>>>(Xh, WqsT, WksT, WvsT,
                                                    Qh, Kh, Vh,
                                                    nullptr, nullptr, 2048, 1024, 1024);
  gemm16_kernel<<<dim3(16, 8, 1), 256, 0, stream>>>(pos, WrelT, WrelT, WrelT,
                                                    relkh, relkh, relkh,
                                                    nullptr, nullptr, 2048, 1024, 192);

  // 3. V^T prep
  vt_prep_kernel<<<dim3(32, 4, 16), dim3(32, 8), 0, stream>>>(Vh, Vt);

  // 4. fused attention (split-K over 2 slices, pipelined) + combine
  attn_kernel<<<dim3(16, 2, 16), 256, 0, stream>>>(Qh, Kh, Vt, relkh, ebias, pbias,
                                                   Opart, mlpart);
  combine_kernel<<<2048, 256, 0, stream>>>(Opart, mlpart, attnO);

  // 5. output projection + bias (f32 out)
  gemm16_kernel<<<dim3(16, 8, 1), 256, 0, stream>>>(attnO, WoutT, WoutT, WoutT,
                                                    nullptr, nullptr, nullptr,
                                                    out, b_out, 2048, 1024, 1024);
}

// Round 11
// 118.717 us; speedup vs baseline: 1.2947x; 1.2947x over previous
//
#include <hip/hip_runtime.h>
#include <hip/hip_fp16.h>

typedef __attribute__((ext_vector_type(8))) _Float16 f16x8;
typedef __attribute__((ext_vector_type(4))) float f32x4;

#define MFMA16(a, b, c) __builtin_amdgcn_mfma_f32_16x16x32_f16((a), (b), (c), 0, 0, 0)

__device__ __forceinline__ unsigned short f2h(float f) {
  __half h = __float2half(f);
  return __half_as_ushort(h);
}

__device__ __forceinline__ void gll16(const void* g, void* l) {
  __builtin_amdgcn_global_load_lds(
      (const __attribute__((address_space(1))) unsigned int*)g,
      (__attribute__((address_space(3))) unsigned int*)l, 16, 0, 0);
}

// ---------------- f32 -> fp16 convert (vectorized) ----------------
__global__ void cvt_f16_kernel(const float* __restrict__ X, unsigned short* __restrict__ Y) {
  size_t i = ((size_t)blockIdx.x * blockDim.x + threadIdx.x) * 4;
  float4 v = *reinterpret_cast<const float4*>(X + i);
  ushort4 o;
  o.x = f2h(v.x); o.y = f2h(v.y); o.z = f2h(v.z); o.w = f2h(v.w);
  *reinterpret_cast<ushort4*>(Y + i) = o;
}

// ---------------- batched weight transpose f32(1024x1024) -> fp16(1024x1024)^T ----------------
__global__ void transpose_w4_kernel(const float* __restrict__ W0, const float* __restrict__ W1,
                                    const float* __restrict__ W2, const float* __restrict__ W3,
                                    unsigned short* __restrict__ T0, unsigned short* __restrict__ T1,
                                    unsigned short* __restrict__ T2, unsigned short* __restrict__ T3) {
  __shared__ float tile[32][33];
  int z = blockIdx.z;
  const float* W = (z == 0) ? W0 : ((z == 1) ? W1 : ((z == 2) ? W2 : W3));
  unsigned short* WT = (z == 0) ? T0 : ((z == 1) ? T1 : ((z == 2) ? T2 : T3));
  int c0 = blockIdx.x * 32, r0 = blockIdx.y * 32;
  int tx = threadIdx.x, ty = threadIdx.y;  // 32 x 8
#pragma unroll
  for (int i = 0; i < 32; i += 8)
    tile[ty + i][tx] = W[(size_t)(r0 + ty + i) * 1024 + c0 + tx];
  __syncthreads();
#pragma unroll
  for (int i = 0; i < 32; i += 8)
    WT[(size_t)(c0 + ty + i) * 1024 + r0 + tx] = f2h(tile[tx][ty + i]);
}

// ---------------- rel weight transpose f32(192x1024) -> fp16(1024x192) ----------------
__global__ void transpose_wr_kernel(const float* __restrict__ W, unsigned short* __restrict__ WT) {
  __shared__ float tile[32][33];
  int c0 = blockIdx.x * 32, r0 = blockIdx.y * 32;
  int tx = threadIdx.x, ty = threadIdx.y;
#pragma unroll
  for (int i = 0; i < 32; i += 8)
    tile[ty + i][tx] = W[(size_t)(r0 + ty + i) * 1024 + c0 + tx];
  __syncthreads();
#pragma unroll
  for (int i = 0; i < 32; i += 8)
    WT[(size_t)(c0 + ty + i) * 192 + r0 + tx] = f2h(tile[tx][ty + i]);
}

// ---------------- positional embedding (wave-parallel): pos[2048][192] fp16 ----------------
// One 32-lane group per distance d; lane j computes feature j of each family.
__global__ void posembed_kernel(unsigned short* __restrict__ pos) {
  int grp = (blockIdx.x * blockDim.x + threadIdx.x) >> 5;  // distance index 0..2047
  int j = threadIdx.x & 31;
  if (grp >= 2048) return;
  unsigned short* row = pos + (size_t)grp * 192;
  if (grp == 2047) {  // padding row = 0
#pragma unroll
    for (int t = 0; t < 6; ++t) row[t * 32 + j] = 0;
    return;
  }
  float dist = (float)grp - 1023.0f;
  float absd = fabsf(dist);
  float jp = (float)(j + 1);
  float hl = exp2f(3.0f + (float)j * (7.0f / 31.0f));   // 2^linspace(3,10,32)
  float fe = exp2f(-absd / hl);                          // exp(-ln2/hl*absd)
  float cw = exp2f(jp) - 1.0f;
  float fc = (cw > absd) ? 1.0f : 0.0f;
  float conc = 4.0f * jp * jp;        // (mean/std)^2
  float rate = 0.125f * jp;           // mean/std^2
  float lu = (conc - 1.0f) * logf(absd) - rate * absd;   // absd=0 -> -inf (xlogy)
  float ln_ = lgammaf(conc) - conc * logf(rate);
  float p = expf(lu - ln_) + 1e-8f;
  float mp = p;
#pragma unroll
  for (int off = 16; off >= 1; off >>= 1) mp = fmaxf(mp, __shfl_xor(mp, off));
  float gm = p / mp;
  unsigned short e = f2h(fe), c = f2h(fc), gg = f2h(gm);
  row[j] = e; row[32 + j] = c; row[64 + j] = gg;
  unsigned short se, sc, sg;
  if (dist > 0.0f)      { se = e; sc = c; sg = gg; }
  else if (dist < 0.0f) { se = (unsigned short)(e ^ 0x8000u);
                          sc = (unsigned short)(c ^ 0x8000u);
                          sg = (unsigned short)(gg ^ 0x8000u); }
  else                  { se = 0; sc = 0; sg = 0; }
  row[96 + j] = se; row[128 + j] = sc; row[160 + j] = sg;
}

// ---------------- fp16 GEMM (m97 structure): C = A[M,K] @ BT[N,K]^T ----------------
__global__ __launch_bounds__(256) void gemm16_kernel(
    const unsigned short* __restrict__ A,
    const unsigned short* __restrict__ BT0, const unsigned short* __restrict__ BT1,
    const unsigned short* __restrict__ BT2,
    unsigned short* __restrict__ D0, unsigned short* __restrict__ D1,
    unsigned short* __restrict__ D2,
    float* __restrict__ C32, const float* __restrict__ bias,
    int M, int N, int K) {
  __shared__ unsigned short As[128][64];  // linear (gll dest), logically XOR-swizzled
  __shared__ unsigned short Bs[128][64];
  const unsigned short* BT = (blockIdx.z == 0) ? BT0 : ((blockIdx.z == 1) ? BT1 : BT2);
  unsigned short* D = (blockIdx.z == 0) ? D0 : ((blockIdx.z == 1) ? D1 : D2);

  int tid = threadIdx.x, wave = tid >> 6, lane = tid & 63;
  int g = lane >> 4, r16 = lane & 15;
  int wr = wave >> 1, wc = wave & 1;
  int m0 = blockIdx.x * 128, n0 = blockIdx.y * 128;
  int srow = wave * 32 + (lane >> 3);  // + 8*i
  int scb = lane & 7;                  // physical 16B slot within row

  f32x4 acc[4][4] = {};

  for (int k0 = 0; k0 < K; k0 += 64) {
    __syncthreads();
#pragma unroll
    for (int i = 0; i < 4; ++i) {
      int row = srow + i * 8;
      int cb = scb ^ (row & 7);  // pre-swizzled global source, linear LDS dest
      gll16(A + (size_t)(m0 + row) * K + k0 + cb * 8, &As[row][scb * 8]);
      gll16(BT + (size_t)(n0 + row) * K + k0 + cb * 8, &Bs[row][scb * 8]);
    }
    asm volatile("s_waitcnt vmcnt(0)" ::: "memory");
    __syncthreads();

    f16x8 af[2][4], bfr[2][4];
#pragma unroll
    for (int kf = 0; kf < 2; ++kf) {
#pragma unroll
      for (int mt = 0; mt < 4; ++mt) {
        int R = wr * 64 + mt * 16 + r16;
        af[kf][mt] = *reinterpret_cast<const f16x8*>(&As[R][(((kf * 4 + g)) ^ (R & 7)) * 8]);
      }
#pragma unroll
      for (int nt = 0; nt < 4; ++nt) {
        int R = wc * 64 + nt * 16 + r16;
        bfr[kf][nt] = *reinterpret_cast<const f16x8*>(&Bs[R][(((kf * 4 + g)) ^ (R & 7)) * 8]);
      }
    }
#pragma unroll
    for (int kf = 0; kf < 2; ++kf)
#pragma unroll
      for (int mt = 0; mt < 4; ++mt)
#pragma unroll
        for (int nt = 0; nt < 4; ++nt)
          acc[mt][nt] = MFMA16(af[kf][mt], bfr[kf][nt], acc[mt][nt]);
  }

#pragma unroll
  for (int nt = 0; nt < 4; ++nt) {
    int col = n0 + wc * 64 + nt * 16 + r16;
    float bv = (C32 && bias) ? bias[col] : 0.0f;
#pragma unroll
    for (int mt = 0; mt < 4; ++mt) {
      int rowb = m0 + wr * 64 + mt * 16 + g * 4;
      if (C32) {
#pragma unroll
        for (int rg = 0; rg < 4; ++rg)
          C32[(size_t)(rowb + rg) * N + col] = acc[mt][nt][rg] + bv;
      } else {
#pragma unroll
        for (int rg = 0; rg < 4; ++rg)
          D[(size_t)(rowb + rg) * N + col] = f2h(acc[mt][nt][rg]);
      }
    }
  }
}

// ---------------- V transpose prep: Vh fp16 (2048x1024) -> Vt fp16 [bh][128][1024] ----------------
__global__ void vt_prep_kernel(const unsigned short* __restrict__ Vh, unsigned short* __restrict__ Vt) {
  __shared__ unsigned short tile[32][34];
  int bh = blockIdx.z;
  int b = bh >> 3, h = bh & 7;
  int l0 = blockIdx.x * 32, n0 = blockIdx.y * 32;
  int tx = threadIdx.x, ty = threadIdx.y;
#pragma unroll
  for (int i = 0; i < 32; i += 8)
    tile[ty + i][tx] = Vh[(size_t)(b * 1024 + l0 + ty + i) * 1024 + h * 128 + n0 + tx];
  __syncthreads();
#pragma unroll
  for (int i = 0; i < 32; i += 8)
    Vt[(size_t)bh * 131072 + (size_t)(n0 + ty + i) * 1024 + l0 + tx] = tile[tx][ty + i];
}

// ---------------- fused attention v6: 2-phase pipeline, R ring, deferred softmax ----------------
// grid (L/64, 2, B*H); 4 waves; wave owns 16 q rows; BK=32; online softmax.
// Per iter: vmcnt(0) -> ds_write V[t] -> barrier -> issue K/R/V[t+1] -> compute t.
__global__ __launch_bounds__(256) void attn_kernel(
    const unsigned short* __restrict__ Qh, const unsigned short* __restrict__ Kh,
    const unsigned short* __restrict__ Vt, const unsigned short* __restrict__ relkh,
    const float* __restrict__ eb, const float* __restrict__ pb,
    unsigned short* __restrict__ Opart, float* __restrict__ mlpart) {
  __shared__ unsigned short Ks[2][32 * 128];   // 16KB dbuf, swizzled slots
  __shared__ unsigned short Rs[128 * 128];     // 32KB ring (slot = row & 127), swizzled slots
  __shared__ unsigned short Vs[2][128][40];    // 20KB dbuf, padded
  __shared__ unsigned short Ps[4][16][42];     // 5.25KB

  int tid = threadIdx.x;
  int wave = tid >> 6, lane = tid & 63;
  int g = lane >> 4, r16 = lane & 15;
  int ks = blockIdx.y;
  int bh = blockIdx.z;
  int b = bh >> 3, h = bh & 7;
  int q0 = blockIdx.x * 64;
  int q0w = q0 + wave * 16;
  const float scale = 0.0883883476483184f;  // 128^-0.5

  // ---- Q fragments (A-layout: row = lane&15, k = (lane>>4)*8+i), two bias variants
  f16x8 qa[4], qbv[4];
  {
    int qrow = b * 1024 + q0w + r16;
    const unsigned short* qp = Qh + (size_t)qrow * 1024 + h * 128;
    const float* ebp = eb + h * 128;
    const float* pbp = pb + h * 128;
#pragma unroll
    for (int kf = 0; kf < 4; ++kf) {
      int dbase = kf * 32 + g * 8;
      uint4 qv = *reinterpret_cast<const uint4*>(qp + dbase);
      const __half* hv = reinterpret_cast<const __half*>(&qv);
      float4 e0 = *reinterpret_cast<const float4*>(ebp + dbase);
      float4 e1 = *reinterpret_cast<const float4*>(ebp + dbase + 4);
      float4 c0 = *reinterpret_cast<const float4*>(pbp + dbase);
      float4 c1 = *reinterpret_cast<const float4*>(pbp + dbase + 4);
      float ev[8] = {e0.x, e0.y, e0.z, e0.w, e1.x, e1.y, e1.z, e1.w};
      float bv[8] = {c0.x, c0.y, c0.z, c0.w, c1.x, c1.y, c1.z, c1.w};
      unsigned short ta[8], tb[8];
#pragma unroll
      for (int i = 0; i < 8; ++i) {
        float s = __half2float(hv[i]) * scale;
        ta[i] = f2h(s + ev[i]);
        tb[i] = f2h(s + bv[i]);
      }
      qa[kf] = *reinterpret_cast<f16x8*>(ta);
      qbv[kf] = *reinterpret_cast<f16x8*>(tb);
    }
  }

  float m_run[4], l_part[4];
#pragma unroll
  for (int rg = 0; rg < 4; ++rg) { m_run[rg] = -1e30f; l_part[rg] = 0.0f; }
  f32x4 o_acc[8] = {};

  const unsigned short* KB = Kh + ((size_t)b * 1024) * 1024 + h * 128;
  const unsigned short* VB = Vt + (size_t)bh * 131072;
  const unsigned short* RB = relkh + h * 128;
  int wb = 48 - wave * 16;

  const int t0 = ks * 16, t1 = t0 + 16;
  const int rb0 = 960 + t0 * 32 - q0;

  // ---- prologue: issue K[t0] (2 gll), R window [rb0, rb0+96) (6 gll), V[t0] (2 reg loads)
  uint4 va, vb2;
#pragma unroll
  for (int i = 0; i < 2; ++i) {
    int j = i * 256 + tid;
    int row = j >> 4, s = j & 15, c = s ^ (row & 7);
    gll16(KB + (size_t)(t0 * 32 + row) * 1024 + c * 8, &Ks[t0 & 1][(row * 16 + s) * 8]);
  }
#pragma unroll
  for (int i = 0; i < 6; ++i) {
    int j = i * 256 + tid;
    int row = rb0 + (j >> 4);
    int s = j & 15, c = s ^ (row & 7);
    gll16(RB + (size_t)row * 1024 + c * 8, &Rs[(((row & 127) * 16) + s) * 8]);
  }
  {
    const unsigned short* src = VB + (size_t)(tid >> 1) * 1024 + t0 * 32 + (tid & 1) * 16;
    va = *reinterpret_cast<const uint4*>(src);
    vb2 = *reinterpret_cast<const uint4*>(src + 8);
  }

  for (int t = t0; t < t1; ++t) {
    int cur = t & 1;
    asm volatile("s_waitcnt vmcnt(0)" ::: "memory");
    // write V[t] into dbuf
    {
      int rr = tid >> 1, cc = (tid & 1) * 16;
      *reinterpret_cast<uint4*>(&Vs[cur][rr][cc]) = va;
      *reinterpret_cast<uint4*>(&Vs[cur][rr][cc + 8]) = vb2;
    }
    __syncthreads();

    // ---- issue next tile's loads (stay in flight across compute)
    if (t + 1 < t1) {
      int nk0 = (t + 1) * 32;
#pragma unroll
      for (int i = 0; i < 2; ++i) {
        int j = i * 256 + tid;
        int row = j >> 4, s = j & 15, c = s ^ (row & 7);
        gll16(KB + (size_t)(nk0 + row) * 1024 + c * 8, &Ks[(t + 1) & 1][(row * 16 + s) * 8]);
      }
      int rnew = rb0 + 96 + (t - t0) * 32;
#pragma unroll
      for (int i = 0; i < 2; ++i) {
        int j = i * 256 + tid;
        int row = rnew + (j >> 4);
        int s = j & 15, c = s ^ (row & 7);
        gll16(RB + (size_t)row * 1024 + c * 8, &Rs[(((row & 127) * 16) + s) * 8]);
      }
      const unsigned short* src = VB + (size_t)(tid >> 1) * 1024 + nk0 + (tid & 1) * 16;
      va = *reinterpret_cast<const uint4*>(src);
      vb2 = *reinterpret_cast<const uint4*>(src + 8);
    }

    // ---- compute tile t
    int k0 = t * 32;
    int rbt = rb0 + (t - t0) * 32;
    f32x4 s0 = {0.f, 0.f, 0.f, 0.f}, s1 = {0.f, 0.f, 0.f, 0.f};
    f32x4 w0 = {0.f, 0.f, 0.f, 0.f}, w1 = {0.f, 0.f, 0.f, 0.f}, w2 = {0.f, 0.f, 0.f, 0.f};
#pragma unroll
    for (int kf = 0; kf < 4; ++kf) {
      int sl = kf * 4 + g;
      int x = sl ^ (r16 & 7);
      f16x8 kb0 = *reinterpret_cast<const f16x8*>(&Ks[cur][(r16 * 16 + x) * 8]);
      f16x8 kb1 = *reinterpret_cast<const f16x8*>(&Ks[cur][((16 + r16) * 16 + x) * 8]);
      s0 = MFMA16(qa[kf], kb0, s0);
      s1 = MFMA16(qa[kf], kb1, s1);
      int R0 = rbt + wb + r16, R1 = R0 + 16, R2 = R0 + 32;
      f16x8 rb_0 = *reinterpret_cast<const f16x8*>(&Rs[((R0 & 127) * 16 + (sl ^ (R0 & 7))) * 8]);
      f16x8 rb_1 = *reinterpret_cast<const f16x8*>(&Rs[((R1 & 127) * 16 + (sl ^ (R1 & 7))) * 8]);
      f16x8 rb_2 = *reinterpret_cast<const f16x8*>(&Rs[((R2 & 127) * 16 + (sl ^ (R2 & 7))) * 8]);
      w0 = MFMA16(qbv[kf], rb_0, w0);
      w1 = MFMA16(qbv[kf], rb_1, w1);
      w2 = MFMA16(qbv[kf], rb_2, w2);
    }

    // ---- diagonal gather via funnel shuffle: S2[q'][k'] = W[q'][k'-q'+15]
    float sv[2][4];
#pragma unroll
    for (int rg = 0; rg < 4; ++rg) {
      int qp = g * 4 + rg;
      int idx = r16 + 15 - qp;                  // 0..30
      int srcl = (lane & 48) | (idx & 15);
      float a0 = __shfl(w0[rg], srcl);
      float a1 = __shfl(w1[rg], srcl);
      float a2 = __shfl(w2[rg], srcl);
      bool lo = idx < 16;
      sv[0][rg] = s0[rg] + (lo ? a0 : a1);
      sv[1][rg] = s1[rg] + (lo ? a1 : a2);
    }

    // ---- deferred softmax: conditional rescale (T13), per-lane partial l
    float d = -1e30f;
#pragma unroll
    for (int rg = 0; rg < 4; ++rg)
      d = fmaxf(d, fmaxf(sv[0][rg], sv[1][rg]) - m_run[rg]);
    if (!__all(d <= 8.0f)) {
#pragma unroll
      for (int rg = 0; rg < 4; ++rg) {
        float mx = fmaxf(sv[0][rg], sv[1][rg]);
#pragma unroll
        for (int off = 8; off >= 1; off >>= 1) mx = fmaxf(mx, __shfl_xor(mx, off));
        float mnew = fmaxf(m_run[rg], mx);
        float scl = __expf(m_run[rg] - mnew);
        l_part[rg] *= scl;
#pragma unroll
        for (int nf = 0; nf < 8; ++nf) o_acc[nf][rg] *= scl;
        m_run[rg] = mnew;
      }
    }
#pragma unroll
    for (int rg = 0; rg < 4; ++rg) {
      float e0 = __expf(sv[0][rg] - m_run[rg]);
      float e1 = __expf(sv[1][rg] - m_run[rg]);
      l_part[rg] += e0 + e1;
      Ps[wave][g * 4 + rg][r16] = f2h(e0);
      Ps[wave][g * 4 + rg][16 + r16] = f2h(e1);
    }
    // ---- PV: O += P (16x32) . V (32x128)
    f16x8 pf = *reinterpret_cast<const f16x8*>(&Ps[wave][r16][g * 8]);
#pragma unroll
    for (int nf = 0; nf < 8; ++nf) {
      f16x8 vb = *reinterpret_cast<const f16x8*>(&Vs[cur][nf * 16 + r16][g * 8]);
      o_acc[nf] = MFMA16(pf, vb, o_acc[nf]);
    }
  }

  // ---- final l reduction across the 16-lane row group
  float l_run[4];
#pragma unroll
  for (int rg = 0; rg < 4; ++rg) {
    float rs = l_part[rg];
#pragma unroll
    for (int off = 8; off >= 1; off >>= 1) rs += __shfl_xor(rs, off);
    l_run[rg] = rs;
  }

  // epilogue: write unnormalized O (fp16) + (m,l) partials
  size_t slice = (size_t)(ks * 16 + bh);
#pragma unroll
  for (int rg = 0; rg < 4; ++rg) {
    unsigned short* op = Opart + (slice * 1024 + q0w + g * 4 + rg) * 128;
#pragma unroll
    for (int nf = 0; nf < 8; ++nf) op[nf * 16 + r16] = f2h(o_acc[nf][rg]);
  }
  if (r16 == 0) {
#pragma unroll
    for (int rg = 0; rg < 4; ++rg) {
      float2 ml = {m_run[rg], l_run[rg]};
      *reinterpret_cast<float2*>(mlpart + (slice * 1024 + q0w + g * 4 + rg) * 2) = ml;
    }
  }
}

// ---------------- combine two k-slices -> attnO fp16 ----------------
__global__ void combine_kernel(const unsigned short* __restrict__ Opart,
                               const float* __restrict__ mlpart,
                               unsigned short* __restrict__ attnO) {
  int idx = blockIdx.x * 256 + threadIdx.x;  // 16*1024*32 threads
  int d4 = (idx & 31) * 4;
  int qq = (idx >> 5) & 1023;
  int bh = idx >> 15;
  float2 ml[2];
  float m = -1e30f;
#pragma unroll
  for (int s = 0; s < 2; ++s) {
    ml[s] = *reinterpret_cast<const float2*>(mlpart + (((size_t)(s * 16 + bh)) * 1024 + qq) * 2);
    m = fmaxf(m, ml[s].x);
  }
  float num0 = 0.f, num1 = 0.f, num2 = 0.f, num3 = 0.f, den = 0.f;
#pragma unroll
  for (int s = 0; s < 2; ++s) {
    float w = __expf(ml[s].x - m);
    den += w * ml[s].y;
    ushort4 ov = *reinterpret_cast<const ushort4*>(
        Opart + (((size_t)(s * 16 + bh)) * 1024 + qq) * 128 + d4);
    num0 += w * __half2float(__ushort_as_half(ov.x));
    num1 += w * __half2float(__ushort_as_half(ov.y));
    num2 += w * __half2float(__ushort_as_half(ov.z));
    num3 += w * __half2float(__ushort_as_half(ov.w));
  }
  float inv = 1.0f / den;
  ushort4 o;
  o.x = f2h(num0 * inv); o.y = f2h(num1 * inv);
  o.z = f2h(num2 * inv); o.w = f2h(num3 * inv);
  int b = bh >> 3, h = bh & 7;
  *reinterpret_cast<ushort4*>(attnO + ((size_t)(b * 1024 + qq)) * 1024 + h * 128 + d4) = o;
}

// ---------------- launch ----------------
extern "C" void kernel_launch(void* const* d_in, const int* in_sizes, int n_in,
                              void* d_out, int out_size, void* d_ws, size_t ws_size,
                              hipStream_t stream) {
  const float* q      = (const float*)d_in[0];
  const float* w_qs   = (const float*)d_in[1];
  const float* w_ks   = (const float*)d_in[2];
  const float* w_vs   = (const float*)d_in[3];
  const float* w_rel  = (const float*)d_in[4];
  const float* ebias  = (const float*)d_in[5];
  const float* pbias  = (const float*)d_in[6];
  const float* w_out  = (const float*)d_in[7];
  const float* b_out  = (const float*)d_in[8];
  float* out = (float*)d_out;

  char* ws = (char*)d_ws;
  const size_t MB = 1u << 20;
  unsigned short* Xh    = (unsigned short*)(ws + 0 * MB);   // 2048x1024 fp16
  unsigned short* WqsT  = (unsigned short*)(ws + 4 * MB);
  unsigned short* WksT  = (unsigned short*)(ws + 6 * MB);
  unsigned short* WvsT  = (unsigned short*)(ws + 8 * MB);
  unsigned short* WoutT = (unsigned short*)(ws + 10 * MB);
  unsigned short* WrelT = (unsigned short*)(ws + 12 * MB);  // 1024x192
  unsigned short* pos   = (unsigned short*)(ws + 13 * MB);  // 2048x192
  unsigned short* Qh    = (unsigned short*)(ws + 14 * MB);  // 2048x1024 fp16
  unsigned short* Kh    = (unsigned short*)(ws + 18 * MB);
  unsigned short* Vh    = (unsigned short*)(ws + 22 * MB);
  unsigned short* relkh = (unsigned short*)(ws + 26 * MB);  // 2048x1024 fp16
  unsigned short* Vt    = (unsigned short*)(ws + 30 * MB);  // 16x128x1024 fp16
  unsigned short* attnO = (unsigned short*)(ws + 34 * MB);  // 2048x1024 fp16
  unsigned short* Opart = (unsigned short*)(ws + 38 * MB);  // 2x16x1024x128 fp16 (8MB)
  float* mlpart         = (float*)(ws + 50 * MB);           // 2x16x1024x2 f32

  // 1. converts / transposes / positional embed
  cvt_f16_kernel<<<2048, 256, 0, stream>>>(q, Xh);
  transpose_w4_kernel<<<dim3(32, 32, 4), dim3(32, 8), 0, stream>>>(
      w_qs, w_ks, w_vs, w_out, WqsT, WksT, WvsT, WoutT);
  transpose_wr_kernel<<<dim3(32, 6), dim3(32, 8), 0, stream>>>(w_rel, WrelT);
  posembed_kernel<<<256, 256, 0, stream>>>(pos);

  // 2. projections (QKV batched via grid.z) + rel_k, fp16 outputs
  gemm16_kernel<<<dim3(16, 8, 3), 256, 0, stream>>>(Xh, WqsT, WksT, WvsT,
                                                    Qh, Kh, Vh,
                                                    nullptr, nullptr, 2048, 1024, 1024);
  gemm16_kernel<<<dim3(16, 8, 1), 256, 0, stream>>>(pos, WrelT, WrelT, WrelT,
                                                    relkh, relkh, relkh,
                                                    nullptr, nullptr, 2048, 1024, 192);

  // 3. V^T prep
  vt_prep_kernel<<<dim3(32, 4, 16), dim3(32, 8), 0, stream>>>(Vh, Vt);

  // 4. fused attention (split-K over 2 slices, pipelined) + combine
  attn_kernel<<<dim3(16, 2, 16), 256, 0, stream>>>(Qh, Kh, Vt, relkh, ebias, pbias,
                                                   Opart, mlpart);
  combine_kernel<<<2048, 256, 0, stream>>>(Opart, mlpart, attnO);

  // 5. output projection + bias (f32 out)
  gemm16_kernel<<<dim3(16, 8, 1), 256, 0, stream>>>(attnO, WoutT, WoutT, WoutT,
                                                    nullptr, nullptr, nullptr,
                                                    out, b_out, 2048, 1024, 1024);
}

// Round 12
// 111.542 us; speedup vs baseline: 1.3780x; 1.0643x over previous
//
#include <hip/hip_runtime.h>
#include <hip/hip_fp16.h>

typedef __attribute__((ext_vector_type(8))) _Float16 f16x8;
typedef __attribute__((ext_vector_type(4))) float f32x4;

#define MFMA16(a, b, c) __builtin_amdgcn_mfma_f32_16x16x32_f16((a), (b), (c), 0, 0, 0)

__device__ __forceinline__ unsigned short f2h(float f) {
  __half h = __float2half(f);
  return __half_as_ushort(h);
}

__device__ __forceinline__ void gll16(const void* g, void* l) {
  __builtin_amdgcn_global_load_lds(
      (const __attribute__((address_space(1))) unsigned int*)g,
      (__attribute__((address_space(3))) unsigned int*)l, 16, 0, 0);
}

// ---------------- f32 -> fp16 convert (vectorized) ----------------
__global__ void cvt_f16_kernel(const float* __restrict__ X, unsigned short* __restrict__ Y) {
  size_t i = ((size_t)blockIdx.x * blockDim.x + threadIdx.x) * 4;
  float4 v = *reinterpret_cast<const float4*>(X + i);
  ushort4 o;
  o.x = f2h(v.x); o.y = f2h(v.y); o.z = f2h(v.z); o.w = f2h(v.w);
  *reinterpret_cast<ushort4*>(Y + i) = o;
}

// ---------------- batched weight transpose f32(1024x1024) -> fp16(1024x1024)^T ----------------
__global__ void transpose_w4_kernel(const float* __restrict__ W0, const float* __restrict__ W1,
                                    const float* __restrict__ W2, const float* __restrict__ W3,
                                    unsigned short* __restrict__ T0, unsigned short* __restrict__ T1,
                                    unsigned short* __restrict__ T2, unsigned short* __restrict__ T3) {
  __shared__ float tile[32][33];
  int z = blockIdx.z;
  const float* W = (z == 0) ? W0 : ((z == 1) ? W1 : ((z == 2) ? W2 : W3));
  unsigned short* WT = (z == 0) ? T0 : ((z == 1) ? T1 : ((z == 2) ? T2 : T3));
  int c0 = blockIdx.x * 32, r0 = blockIdx.y * 32;
  int tx = threadIdx.x, ty = threadIdx.y;  // 32 x 8
#pragma unroll
  for (int i = 0; i < 32; i += 8)
    tile[ty + i][tx] = W[(size_t)(r0 + ty + i) * 1024 + c0 + tx];
  __syncthreads();
#pragma unroll
  for (int i = 0; i < 32; i += 8)
    WT[(size_t)(c0 + ty + i) * 1024 + r0 + tx] = f2h(tile[tx][ty + i]);
}

// ---------------- rel weight transpose f32(192x1024) -> fp16(1024x192) ----------------
__global__ void transpose_wr_kernel(const float* __restrict__ W, unsigned short* __restrict__ WT) {
  __shared__ float tile[32][33];
  int c0 = blockIdx.x * 32, r0 = blockIdx.y * 32;
  int tx = threadIdx.x, ty = threadIdx.y;
#pragma unroll
  for (int i = 0; i < 32; i += 8)
    tile[ty + i][tx] = W[(size_t)(r0 + ty + i) * 1024 + c0 + tx];
  __syncthreads();
#pragma unroll
  for (int i = 0; i < 32; i += 8)
    WT[(size_t)(c0 + ty + i) * 192 + r0 + tx] = f2h(tile[tx][ty + i]);
}

// ---------------- positional embedding (wave-parallel): pos[2048][192] fp16 ----------------
__global__ void posembed_kernel(unsigned short* __restrict__ pos) {
  int grp = (blockIdx.x * blockDim.x + threadIdx.x) >> 5;  // distance index 0..2047
  int j = threadIdx.x & 31;
  if (grp >= 2048) return;
  unsigned short* row = pos + (size_t)grp * 192;
  if (grp == 2047) {  // padding row = 0
#pragma unroll
    for (int t = 0; t < 6; ++t) row[t * 32 + j] = 0;
    return;
  }
  float dist = (float)grp - 1023.0f;
  float absd = fabsf(dist);
  float jp = (float)(j + 1);
  float hl = exp2f(3.0f + (float)j * (7.0f / 31.0f));
  float fe = exp2f(-absd / hl);
  float cw = exp2f(jp) - 1.0f;
  float fc = (cw > absd) ? 1.0f : 0.0f;
  float conc = 4.0f * jp * jp;
  float rate = 0.125f * jp;
  float lu = (conc - 1.0f) * logf(absd) - rate * absd;
  float ln_ = lgammaf(conc) - conc * logf(rate);
  float p = expf(lu - ln_) + 1e-8f;
  float mp = p;
#pragma unroll
  for (int off = 16; off >= 1; off >>= 1) mp = fmaxf(mp, __shfl_xor(mp, off));
  float gm = p / mp;
  unsigned short e = f2h(fe), c = f2h(fc), gg = f2h(gm);
  row[j] = e; row[32 + j] = c; row[64 + j] = gg;
  unsigned short se, sc, sg;
  if (dist > 0.0f)      { se = e; sc = c; sg = gg; }
  else if (dist < 0.0f) { se = (unsigned short)(e ^ 0x8000u);
                          sc = (unsigned short)(c ^ 0x8000u);
                          sg = (unsigned short)(gg ^ 0x8000u); }
  else                  { se = 0; sc = 0; sg = 0; }
  row[96 + j] = se; row[128 + j] = sc; row[160 + j] = sg;
}

// ---------------- fused fp16 GEMM (QKV + rel): D_z = A_z @ BT_z^T, fp16 out ----------------
// z<3: A (M=2048,K=1024); z==3: A3 (M=2048,K=192). 128x128 tile, BK=64, gll w16, XOR swizzle.
__global__ __launch_bounds__(256) void gemm16_kernel(
    const unsigned short* __restrict__ A, const unsigned short* __restrict__ A3,
    const unsigned short* __restrict__ BT0, const unsigned short* __restrict__ BT1,
    const unsigned short* __restrict__ BT2, const unsigned short* __restrict__ BT3,
    unsigned short* __restrict__ D0, unsigned short* __restrict__ D1,
    unsigned short* __restrict__ D2, unsigned short* __restrict__ D3,
    int Kmain, int K3) {
  __shared__ unsigned short As[128][64];
  __shared__ unsigned short Bs[128][64];
  int z = blockIdx.z;
  const unsigned short* Az = (z == 3) ? A3 : A;
  const unsigned short* BT = (z == 0) ? BT0 : ((z == 1) ? BT1 : ((z == 2) ? BT2 : BT3));
  unsigned short* D = (z == 0) ? D0 : ((z == 1) ? D1 : ((z == 2) ? D2 : D3));
  int K = (z == 3) ? K3 : Kmain;
  const int N = 1024;

  int tid = threadIdx.x, wave = tid >> 6, lane = tid & 63;
  int g = lane >> 4, r16 = lane & 15;
  int wr = wave >> 1, wc = wave & 1;
  int m0 = blockIdx.x * 128, n0 = blockIdx.y * 128;
  int srow = wave * 32 + (lane >> 3);
  int scb = lane & 7;

  f32x4 acc[4][4] = {};

  for (int k0 = 0; k0 < K; k0 += 64) {
    __syncthreads();
#pragma unroll
    for (int i = 0; i < 4; ++i) {
      int row = srow + i * 8;
      int cb = scb ^ (row & 7);
      gll16(Az + (size_t)(m0 + row) * K + k0 + cb * 8, &As[row][scb * 8]);
      gll16(BT + (size_t)(n0 + row) * K + k0 + cb * 8, &Bs[row][scb * 8]);
    }
    asm volatile("s_waitcnt vmcnt(0)" ::: "memory");
    __syncthreads();

    f16x8 af[2][4], bfr[2][4];
#pragma unroll
    for (int kf = 0; kf < 2; ++kf) {
#pragma unroll
      for (int mt = 0; mt < 4; ++mt) {
        int R = wr * 64 + mt * 16 + r16;
        af[kf][mt] = *reinterpret_cast<const f16x8*>(&As[R][(((kf * 4 + g)) ^ (R & 7)) * 8]);
      }
#pragma unroll
      for (int nt = 0; nt < 4; ++nt) {
        int R = wc * 64 + nt * 16 + r16;
        bfr[kf][nt] = *reinterpret_cast<const f16x8*>(&Bs[R][(((kf * 4 + g)) ^ (R & 7)) * 8]);
      }
    }
#pragma unroll
    for (int kf = 0; kf < 2; ++kf)
#pragma unroll
      for (int mt = 0; mt < 4; ++mt)
#pragma unroll
        for (int nt = 0; nt < 4; ++nt)
          acc[mt][nt] = MFMA16(af[kf][mt], bfr[kf][nt], acc[mt][nt]);
  }

#pragma unroll
  for (int nt = 0; nt < 4; ++nt) {
    int col = n0 + wc * 64 + nt * 16 + r16;
#pragma unroll
    for (int mt = 0; mt < 4; ++mt) {
      int rowb = m0 + wr * 64 + mt * 16 + g * 4;
#pragma unroll
      for (int rg = 0; rg < 4; ++rg)
        D[(size_t)(rowb + rg) * N + col] = f2h(acc[mt][nt][rg]);
    }
  }
}

// ---------------- out-proj: split-K=2, f32 atomicAdd into pre-biased out ----------------
__global__ void bias_init_kernel(const float* __restrict__ b, float* __restrict__ out) {
  size_t i = ((size_t)blockIdx.x * 256 + threadIdx.x) * 4;
  float4 bv = *reinterpret_cast<const float4*>(b + (i & 1023));
  *reinterpret_cast<float4*>(out + i) = bv;
}

__global__ __launch_bounds__(256) void gemm16_atomic_kernel(
    const unsigned short* __restrict__ A, const unsigned short* __restrict__ BT,
    float* __restrict__ C) {
  __shared__ unsigned short As[128][64];
  __shared__ unsigned short Bs[128][64];
  const int N = 1024, K = 1024;
  int tid = threadIdx.x, wave = tid >> 6, lane = tid & 63;
  int g = lane >> 4, r16 = lane & 15;
  int wr = wave >> 1, wc = wave & 1;
  int m0 = blockIdx.x * 128, n0 = blockIdx.y * 128;
  int kb = blockIdx.z * 512;
  int srow = wave * 32 + (lane >> 3);
  int scb = lane & 7;

  f32x4 acc[4][4] = {};

  for (int k0 = kb; k0 < kb + 512; k0 += 64) {
    __syncthreads();
#pragma unroll
    for (int i = 0; i < 4; ++i) {
      int row = srow + i * 8;
      int cb = scb ^ (row & 7);
      gll16(A + (size_t)(m0 + row) * K + k0 + cb * 8, &As[row][scb * 8]);
      gll16(BT + (size_t)(n0 + row) * K + k0 + cb * 8, &Bs[row][scb * 8]);
    }
    asm volatile("s_waitcnt vmcnt(0)" ::: "memory");
    __syncthreads();

    f16x8 af[2][4], bfr[2][4];
#pragma unroll
    for (int kf = 0; kf < 2; ++kf) {
#pragma unroll
      for (int mt = 0; mt < 4; ++mt) {
        int R = wr * 64 + mt * 16 + r16;
        af[kf][mt] = *reinterpret_cast<const f16x8*>(&As[R][(((kf * 4 + g)) ^ (R & 7)) * 8]);
      }
#pragma unroll
      for (int nt = 0; nt < 4; ++nt) {
        int R = wc * 64 + nt * 16 + r16;
        bfr[kf][nt] = *reinterpret_cast<const f16x8*>(&Bs[R][(((kf * 4 + g)) ^ (R & 7)) * 8]);
      }
    }
#pragma unroll
    for (int kf = 0; kf < 2; ++kf)
#pragma unroll
      for (int mt = 0; mt < 4; ++mt)
#pragma unroll
        for (int nt = 0; nt < 4; ++nt)
          acc[mt][nt] = MFMA16(af[kf][mt], bfr[kf][nt], acc[mt][nt]);
  }

#pragma unroll
  for (int nt = 0; nt < 4; ++nt) {
    int col = n0 + wc * 64 + nt * 16 + r16;
#pragma unroll
    for (int mt = 0; mt < 4; ++mt) {
      int rowb = m0 + wr * 64 + mt * 16 + g * 4;
#pragma unroll
      for (int rg = 0; rg < 4; ++rg)
        atomicAdd(&C[(size_t)(rowb + rg) * N + col], acc[mt][nt][rg]);
    }
  }
}

// ---------------- V transpose prep: Vh fp16 (2048x1024) -> Vt fp16 [bh][128][1024] ----------------
__global__ void vt_prep_kernel(const unsigned short* __restrict__ Vh, unsigned short* __restrict__ Vt) {
  __shared__ unsigned short tile[32][34];
  int bh = blockIdx.z;
  int b = bh >> 3, h = bh & 7;
  int l0 = blockIdx.x * 32, n0 = blockIdx.y * 32;
  int tx = threadIdx.x, ty = threadIdx.y;
#pragma unroll
  for (int i = 0; i < 32; i += 8)
    tile[ty + i][tx] = Vh[(size_t)(b * 1024 + l0 + ty + i) * 1024 + h * 128 + n0 + tx];
  __syncthreads();
#pragma unroll
  for (int i = 0; i < 32; i += 8)
    Vt[(size_t)bh * 131072 + (size_t)(n0 + ty + i) * 1024 + l0 + tx] = tile[tx][ty + i];
}

// ---------------- fused attention v7: v6 pipeline + XCD-chunked block swizzle ----------------
// grid (16, 2, 16) = 512 blocks; swizzle so each XCD owns 64 consecutive logical blocks
// (= 2 bh groups) -> K/V/R stay resident in that XCD's private L2.
__global__ __launch_bounds__(256) void attn_kernel(
    const unsigned short* __restrict__ Qh, const unsigned short* __restrict__ Kh,
    const unsigned short* __restrict__ Vt, const unsigned short* __restrict__ relkh,
    const float* __restrict__ eb, const float* __restrict__ pb,
    unsigned short* __restrict__ Opart, float* __restrict__ mlpart) {
  __shared__ unsigned short Ks[2][32 * 128];   // 16KB dbuf, swizzled slots
  __shared__ unsigned short Rs[128 * 128];     // 32KB ring (slot = row & 127), swizzled slots
  __shared__ unsigned short Vs[2][128][40];    // 20KB dbuf, padded
  __shared__ unsigned short Ps[4][16][40];     // 5KB (16B-aligned rows)

  int tid = threadIdx.x;
  int wave = tid >> 6, lane = tid & 63;
  int g = lane >> 4, r16 = lane & 15;

  // XCD-chunked bijective swizzle: 512 blocks = 8 XCDs x 64
  int lin = blockIdx.x + 16 * (blockIdx.y + 2 * blockIdx.z);
  int swz = (lin & 7) * 64 + (lin >> 3);
  int ks = (swz >> 4) & 1;
  int bh = swz >> 5;
  int b = bh >> 3, h = bh & 7;
  int q0 = (swz & 15) * 64;
  int q0w = q0 + wave * 16;
  const float scale = 0.0883883476483184f;  // 128^-0.5

  // ---- Q fragments (A-layout), two bias variants
  f16x8 qa[4], qbv[4];
  {
    int qrow = b * 1024 + q0w + r16;
    const unsigned short* qp = Qh + (size_t)qrow * 1024 + h * 128;
    const float* ebp = eb + h * 128;
    const float* pbp = pb + h * 128;
#pragma unroll
    for (int kf = 0; kf < 4; ++kf) {
      int dbase = kf * 32 + g * 8;
      uint4 qv = *reinterpret_cast<const uint4*>(qp + dbase);
      const __half* hv = reinterpret_cast<const __half*>(&qv);
      float4 e0 = *reinterpret_cast<const float4*>(ebp + dbase);
      float4 e1 = *reinterpret_cast<const float4*>(ebp + dbase + 4);
      float4 c0 = *reinterpret_cast<const float4*>(pbp + dbase);
      float4 c1 = *reinterpret_cast<const float4*>(pbp + dbase + 4);
      float ev[8] = {e0.x, e0.y, e0.z, e0.w, e1.x, e1.y, e1.z, e1.w};
      float bv[8] = {c0.x, c0.y, c0.z, c0.w, c1.x, c1.y, c1.z, c1.w};
      unsigned short ta[8], tb[8];
#pragma unroll
      for (int i = 0; i < 8; ++i) {
        float s = __half2float(hv[i]) * scale;
        ta[i] = f2h(s + ev[i]);
        tb[i] = f2h(s + bv[i]);
      }
      qa[kf] = *reinterpret_cast<f16x8*>(ta);
      qbv[kf] = *reinterpret_cast<f16x8*>(tb);
    }
  }

  float m_run[4], l_part[4];
#pragma unroll
  for (int rg = 0; rg < 4; ++rg) { m_run[rg] = -1e30f; l_part[rg] = 0.0f; }
  f32x4 o_acc[8] = {};

  const unsigned short* KB = Kh + ((size_t)b * 1024) * 1024 + h * 128;
  const unsigned short* VB = Vt + (size_t)bh * 131072;
  const unsigned short* RB = relkh + h * 128;
  int wb = 48 - wave * 16;

  const int t0 = ks * 16, t1 = t0 + 16;
  const int rb0 = 960 + t0 * 32 - q0;

  // ---- prologue: issue K[t0], R window [rb0, rb0+96), V[t0]
  uint4 va, vb2;
#pragma unroll
  for (int i = 0; i < 2; ++i) {
    int j = i * 256 + tid;
    int row = j >> 4, s = j & 15, c = s ^ (row & 7);
    gll16(KB + (size_t)(t0 * 32 + row) * 1024 + c * 8, &Ks[t0 & 1][(row * 16 + s) * 8]);
  }
#pragma unroll
  for (int i = 0; i < 6; ++i) {
    int j = i * 256 + tid;
    int row = rb0 + (j >> 4);
    int s = j & 15, c = s ^ (row & 7);
    gll16(RB + (size_t)row * 1024 + c * 8, &Rs[(((row & 127) * 16) + s) * 8]);
  }
  {
    const unsigned short* src = VB + (size_t)(tid >> 1) * 1024 + t0 * 32 + (tid & 1) * 16;
    va = *reinterpret_cast<const uint4*>(src);
    vb2 = *reinterpret_cast<const uint4*>(src + 8);
  }

  for (int t = t0; t < t1; ++t) {
    int cur = t & 1;
    asm volatile("s_waitcnt vmcnt(0)" ::: "memory");
    {
      int rr = tid >> 1, cc = (tid & 1) * 16;
      *reinterpret_cast<uint4*>(&Vs[cur][rr][cc]) = va;
      *reinterpret_cast<uint4*>(&Vs[cur][rr][cc + 8]) = vb2;
    }
    __syncthreads();

    // ---- issue next tile's loads
    if (t + 1 < t1) {
      int nk0 = (t + 1) * 32;
#pragma unroll
      for (int i = 0; i < 2; ++i) {
        int j = i * 256 + tid;
        int row = j >> 4, s = j & 15, c = s ^ (row & 7);
        gll16(KB + (size_t)(nk0 + row) * 1024 + c * 8, &Ks[(t + 1) & 1][(row * 16 + s) * 8]);
      }
      int rnew = rb0 + 96 + (t - t0) * 32;
#pragma unroll
      for (int i = 0; i < 2; ++i) {
        int j = i * 256 + tid;
        int row = rnew + (j >> 4);
        int s = j & 15, c = s ^ (row & 7);
        gll16(RB + (size_t)row * 1024 + c * 8, &Rs[(((row & 127) * 16) + s) * 8]);
      }
      const unsigned short* src = VB + (size_t)(tid >> 1) * 1024 + nk0 + (tid & 1) * 16;
      va = *reinterpret_cast<const uint4*>(src);
      vb2 = *reinterpret_cast<const uint4*>(src + 8);
    }

    // ---- compute tile t
    int rbt = rb0 + (t - t0) * 32;
    f32x4 s0 = {0.f, 0.f, 0.f, 0.f}, s1 = {0.f, 0.f, 0.f, 0.f};
    f32x4 w0 = {0.f, 0.f, 0.f, 0.f}, w1 = {0.f, 0.f, 0.f, 0.f}, w2 = {0.f, 0.f, 0.f, 0.f};
#pragma unroll
    for (int kf = 0; kf < 4; ++kf) {
      int sl = kf * 4 + g;
      int x = sl ^ (r16 & 7);
      f16x8 kb0 = *reinterpret_cast<const f16x8*>(&Ks[cur][(r16 * 16 + x) * 8]);
      f16x8 kb1 = *reinterpret_cast<const f16x8*>(&Ks[cur][((16 + r16) * 16 + x) * 8]);
      s0 = MFMA16(qa[kf], kb0, s0);
      s1 = MFMA16(qa[kf], kb1, s1);
      int R0 = rbt + wb + r16, R1 = R0 + 16, R2 = R0 + 32;
      f16x8 rb_0 = *reinterpret_cast<const f16x8*>(&Rs[((R0 & 127) * 16 + (sl ^ (R0 & 7))) * 8]);
      f16x8 rb_1 = *reinterpret_cast<const f16x8*>(&Rs[((R1 & 127) * 16 + (sl ^ (R1 & 7))) * 8]);
      f16x8 rb_2 = *reinterpret_cast<const f16x8*>(&Rs[((R2 & 127) * 16 + (sl ^ (R2 & 7))) * 8]);
      w0 = MFMA16(qbv[kf], rb_0, w0);
      w1 = MFMA16(qbv[kf], rb_1, w1);
      w2 = MFMA16(qbv[kf], rb_2, w2);
    }

    // ---- diagonal gather via funnel shuffle: S2[q'][k'] = W[q'][k'-q'+15]
    float sv[2][4];
#pragma unroll
    for (int rg = 0; rg < 4; ++rg) {
      int qp = g * 4 + rg;
      int idx = r16 + 15 - qp;
      int srcl = (lane & 48) | (idx & 15);
      float a0 = __shfl(w0[rg], srcl);
      float a1 = __shfl(w1[rg], srcl);
      float a2 = __shfl(w2[rg], srcl);
      bool lo = idx < 16;
      sv[0][rg] = s0[rg] + (lo ? a0 : a1);
      sv[1][rg] = s1[rg] + (lo ? a1 : a2);
    }

    // ---- deferred softmax (T13), per-lane partial l
    float d = -1e30f;
#pragma unroll
    for (int rg = 0; rg < 4; ++rg)
      d = fmaxf(d, fmaxf(sv[0][rg], sv[1][rg]) - m_run[rg]);
    if (!__all(d <= 8.0f)) {
#pragma unroll
      for (int rg = 0; rg < 4; ++rg) {
        float mx = fmaxf(sv[0][rg], sv[1][rg]);
#pragma unroll
        for (int off = 8; off >= 1; off >>= 1) mx = fmaxf(mx, __shfl_xor(mx, off));
        float mnew = fmaxf(m_run[rg], mx);
        float scl = __expf(m_run[rg] - mnew);
        l_part[rg] *= scl;
#pragma unroll
        for (int nf = 0; nf < 8; ++nf) o_acc[nf][rg] *= scl;
        m_run[rg] = mnew;
      }
    }
#pragma unroll
    for (int rg = 0; rg < 4; ++rg) {
      float e0 = __expf(sv[0][rg] - m_run[rg]);
      float e1 = __expf(sv[1][rg] - m_run[rg]);
      l_part[rg] += e0 + e1;
      Ps[wave][g * 4 + rg][r16] = f2h(e0);
      Ps[wave][g * 4 + rg][16 + r16] = f2h(e1);
    }
    // ---- PV: O += P (16x32) . V (32x128)
    f16x8 pf = *reinterpret_cast<const f16x8*>(&Ps[wave][r16][g * 8]);
#pragma unroll
    for (int nf = 0; nf < 8; ++nf) {
      f16x8 vb = *reinterpret_cast<const f16x8*>(&Vs[cur][nf * 16 + r16][g * 8]);
      o_acc[nf] = MFMA16(pf, vb, o_acc[nf]);
    }
  }

  // ---- final l reduction across the 16-lane row group
  float l_run[4];
#pragma unroll
  for (int rg = 0; rg < 4; ++rg) {
    float rs = l_part[rg];
#pragma unroll
    for (int off = 8; off >= 1; off >>= 1) rs += __shfl_xor(rs, off);
    l_run[rg] = rs;
  }

  // epilogue
  size_t slice = (size_t)(ks * 16 + bh);
#pragma unroll
  for (int rg = 0; rg < 4; ++rg) {
    unsigned short* op = Opart + (slice * 1024 + q0w + g * 4 + rg) * 128;
#pragma unroll
    for (int nf = 0; nf < 8; ++nf) op[nf * 16 + r16] = f2h(o_acc[nf][rg]);
  }
  if (r16 == 0) {
#pragma unroll
    for (int rg = 0; rg < 4; ++rg) {
      float2 ml = {m_run[rg], l_run[rg]};
      *reinterpret_cast<float2*>(mlpart + (slice * 1024 + q0w + g * 4 + rg) * 2) = ml;
    }
  }
}

// ---------------- combine two k-slices -> attnO fp16 ----------------
__global__ void combine_kernel(const unsigned short* __restrict__ Opart,
                               const float* __restrict__ mlpart,
                               unsigned short* __restrict__ attnO) {
  int idx = blockIdx.x * 256 + threadIdx.x;
  int d4 = (idx & 31) * 4;
  int qq = (idx >> 5) & 1023;
  int bh = idx >> 15;
  float2 ml[2];
  float m = -1e30f;
#pragma unroll
  for (int s = 0; s < 2; ++s) {
    ml[s] = *reinterpret_cast<const float2*>(mlpart + (((size_t)(s * 16 + bh)) * 1024 + qq) * 2);
    m = fmaxf(m, ml[s].x);
  }
  float num0 = 0.f, num1 = 0.f, num2 = 0.f, num3 = 0.f, den = 0.f;
#pragma unroll
  for (int s = 0; s < 2; ++s) {
    float w = __expf(ml[s].x - m);
    den += w * ml[s].y;
    ushort4 ov = *reinterpret_cast<const ushort4*>(
        Opart + (((size_t)(s * 16 + bh)) * 1024 + qq) * 128 + d4);
    num0 += w * __half2float(__ushort_as_half(ov.x));
    num1 += w * __half2float(__ushort_as_half(ov.y));
    num2 += w * __half2float(__ushort_as_half(ov.z));
    num3 += w * __half2float(__ushort_as_half(ov.w));
  }
  float inv = 1.0f / den;
  ushort4 o;
  o.x = f2h(num0 * inv); o.y = f2h(num1 * inv);
  o.z = f2h(num2 * inv); o.w = f2h(num3 * inv);
  int b = bh >> 3, h = bh & 7;
  *reinterpret_cast<ushort4*>(attnO + ((size_t)(b * 1024 + qq)) * 1024 + h * 128 + d4) = o;
}

// ---------------- launch ----------------
extern "C" void kernel_launch(void* const* d_in, const int* in_sizes, int n_in,
                              void* d_out, int out_size, void* d_ws, size_t ws_size,
                              hipStream_t stream) {
  const float* q      = (const float*)d_in[0];
  const float* w_qs   = (const float*)d_in[1];
  const float* w_ks   = (const float*)d_in[2];
  const float* w_vs   = (const float*)d_in[3];
  const float* w_rel  = (const float*)d_in[4];
  const float* ebias  = (const float*)d_in[5];
  const float* pbias  = (const float*)d_in[6];
  const float* w_out  = (const float*)d_in[7];
  const float* b_out  = (const float*)d_in[8];
  float* out = (float*)d_out;

  char* ws = (char*)d_ws;
  const size_t MB = 1u << 20;
  unsigned short* Xh    = (unsigned short*)(ws + 0 * MB);   // 2048x1024 fp16
  unsigned short* WqsT  = (unsigned short*)(ws + 4 * MB);
  unsigned short* WksT  = (unsigned short*)(ws + 6 * MB);
  unsigned short* WvsT  = (unsigned short*)(ws + 8 * MB);
  unsigned short* WoutT = (unsigned short*)(ws + 10 * MB);
  unsigned short* WrelT = (unsigned short*)(ws + 12 * MB);  // 1024x192
  unsigned short* pos   = (unsigned short*)(ws + 13 * MB);  // 2048x192
  unsigned short* Qh    = (unsigned short*)(ws + 14 * MB);  // 2048x1024 fp16
  unsigned short* Kh    = (unsigned short*)(ws + 18 * MB);
  unsigned short* Vh    = (unsigned short*)(ws + 22 * MB);
  unsigned short* relkh = (unsigned short*)(ws + 26 * MB);  // 2048x1024 fp16
  unsigned short* Vt    = (unsigned short*)(ws + 30 * MB);  // 16x128x1024 fp16
  unsigned short* attnO = (unsigned short*)(ws + 34 * MB);  // 2048x1024 fp16
  unsigned short* Opart = (unsigned short*)(ws + 38 * MB);  // 2x16x1024x128 fp16 (8MB)
  float* mlpart         = (float*)(ws + 50 * MB);           // 2x16x1024x2 f32

  // 1. converts / transposes / positional embed
  cvt_f16_kernel<<<2048, 256, 0, stream>>>(q, Xh);
  transpose_w4_kernel<<<dim3(32, 32, 4), dim3(32, 8), 0, stream>>>(
      w_qs, w_ks, w_vs, w_out, WqsT, WksT, WvsT, WoutT);
  transpose_wr_kernel<<<dim3(32, 6), dim3(32, 8), 0, stream>>>(w_rel, WrelT);
  posembed_kernel<<<256, 256, 0, stream>>>(pos);

  // 2. fused projections: QKV (z=0..2, K=1024) + rel_k (z=3, K=192)
  gemm16_kernel<<<dim3(16, 8, 4), 256, 0, stream>>>(
      Xh, pos, WqsT, WksT, WvsT, WrelT, Qh, Kh, Vh, relkh, 1024, 192);

  // 3. V^T prep
  vt_prep_kernel<<<dim3(32, 4, 16), dim3(32, 8), 0, stream>>>(Vh, Vt);

  // 4. fused attention (split-K=2, pipelined, XCD-swizzled) + combine
  attn_kernel<<<dim3(16, 2, 16), 256, 0, stream>>>(Qh, Kh, Vt, relkh, ebias, pbias,
                                                   Opart, mlpart);
  combine_kernel<<<2048, 256, 0, stream>>>(Opart, mlpart, attnO);

  // 5. output projection: out = bias, then split-K=2 atomic GEMM
  bias_init_kernel<<<2048, 256, 0, stream>>>(b_out, out);
  gemm16_atomic_kernel<<<dim3(16, 8, 2), 256, 0, stream>>>(attnO, WoutT, out);
}